// Round 5
// baseline (190.491 us; speedup 1.0000x reference)
//
#include <hip/hip_runtime.h>

// Embedding: out[t, :] = W[:, x[t]] + b   (W [256,100000] row-major f32)
//
// Scatter formulation, round 5: vocab tile widened 16 -> 32 columns.
//   Round-4 k2 read 64 B per row-visit (16 cols) -> random-64B DRAM traffic at
//   ~35% efficiency (2.8 TB/s). 32 cols = 128 B contiguous per row-visit,
//   halves transaction count per byte, doubles per-thread outstanding loads.
//   Also: bin's token list prefetched to LDS (removes ~600cyc latency from the
//   scatter loop), LDS row stride 257 (odd -> staging stores conflict-free).

#define VOCAB 100000
#define EMBED 256
#define NTOK  (32 * 2048)
#define TILEW 32                  // vocab columns per block
#define NTILE (VOCAB / TILEW)     // 3125 bins
#define CAP   128                 // slots per bin (Poisson mean ~21)
#define LSTRIDE 257               // LDS row stride in floats (odd)

// workspace layout (ints): cnt [4096) | list [NTILE*CAP) | flags [NTOK)
#define WS_CNT_OFF   0
#define WS_LIST_OFF  4096
#define WS_FLAG_OFF  (WS_LIST_OFF + NTILE * CAP)
#define WS_INTS      (WS_FLAG_OFF + NTOK)

__global__ __launch_bounds__(256) void k0_zero(int* __restrict__ cnt)
{
    int i = blockIdx.x * 256 + threadIdx.x;
    if (i < NTILE) cnt[i] = 0;
}

__global__ __launch_bounds__(256) void k1_bucket(
    const int* __restrict__ x,
    int* __restrict__ cnt,
    int* __restrict__ list,
    int* __restrict__ flags)
{
    int t = blockIdx.x * 256 + threadIdx.x;
    if (t >= NTOK) return;
    int v   = x[t];
    int bin = v >> 5;                   // v / TILEW
    int i   = v & (TILEW - 1);
    int pos = atomicAdd(&cnt[bin], 1);
    int ovf = (pos >= CAP);
    if (!ovf) list[bin * CAP + pos] = t | (i << 16);   // t<65536, i<32
    flags[t] = ovf;                     // written for ALL t (ws is poisoned)
}

__global__ __launch_bounds__(256) void k2_scatter(
    const float* __restrict__ W,
    const float* __restrict__ bias,
    const int* __restrict__ cnt,
    const int* __restrict__ list,
    float* __restrict__ out)
{
    __shared__ float tileT[TILEW * LSTRIDE];   // [i][e], i=vocab-in-tile, e=embed
    __shared__ int   slist[CAP];

    const int bin = blockIdx.x;
    const int v0  = bin * TILEW;
    const int t   = threadIdx.x;

    // prefetch this bin's token list (contiguous 512 B) before the barrier
    if (t < CAP) slist[t] = list[bin * CAP + t];

    // stage 32x256 tile, transposed, 8 float4 loads/thread.
    // per row e: 8 threads x 16 B = 128 B contiguous (2 cache lines, same page).
    #pragma unroll
    for (int j = 0; j < 8; ++j) {
        const int e  = j * 32 + (t >> 3);
        const int i4 = (t & 7) << 2;
        const float4 w = *reinterpret_cast<const float4*>(
            W + (size_t)e * VOCAB + v0 + i4);
        tileT[(i4 + 0) * LSTRIDE + e] = w.x;
        tileT[(i4 + 1) * LSTRIDE + e] = w.y;
        tileT[(i4 + 2) * LSTRIDE + e] = w.z;
        tileT[(i4 + 3) * LSTRIDE + e] = w.w;
    }
    __syncthreads();

    int n = cnt[bin];
    if (n > CAP) n = CAP;

    const int wave = t >> 6;
    const int lane = t & 63;
    const float4 bv = *reinterpret_cast<const float4*>(bias + lane * 4);

    for (int k = wave; k < n; k += 4) {
        const int packed = slist[k];
        const int tok = packed & 0xFFFF;
        const int i   = packed >> 16;
        const float* src = &tileT[i * LSTRIDE + lane * 4];
        float* dst = out + (size_t)tok * EMBED + lane * 4;
        __builtin_nontemporal_store(src[0] + bv.x, dst + 0);
        __builtin_nontemporal_store(src[1] + bv.y, dst + 1);
        __builtin_nontemporal_store(src[2] + bv.z, dst + 2);
        __builtin_nontemporal_store(src[3] + bv.w, dst + 3);
    }
}

__global__ __launch_bounds__(256) void k3_cleanup(
    const int* __restrict__ x,
    const float* __restrict__ W,
    const float* __restrict__ bias,
    const int* __restrict__ flags,
    float* __restrict__ out)
{
    int t = blockIdx.x * 256 + threadIdx.x;
    if (t >= NTOK) return;
    if (!flags[t]) return;              // never taken for this input
    int v = x[t];
    for (int e = 0; e < EMBED; ++e)
        out[(size_t)t * EMBED + e] = W[(size_t)e * VOCAB + v] + bias[e];
}

// fallback: direct column gather (round-2 kernel), if ws too small
__global__ __launch_bounds__(256) void embed_gather_direct(
    const int* __restrict__ x,
    const float* __restrict__ W,
    const float* __restrict__ bias,
    float* __restrict__ out)
{
    const int tid   = blockIdx.x * blockDim.x + threadIdx.x;
    const int token = tid >> 6;
    const int e     = (tid & 63) << 2;
    if (token >= NTOK) return;
    const int v = x[token];
    const float4 bv = *reinterpret_cast<const float4*>(bias + e);
    float4 r;
    r.x = W[(size_t)(e + 0) * VOCAB + v] + bv.x;
    r.y = W[(size_t)(e + 1) * VOCAB + v] + bv.y;
    r.z = W[(size_t)(e + 2) * VOCAB + v] + bv.z;
    r.w = W[(size_t)(e + 3) * VOCAB + v] + bv.w;
    *reinterpret_cast<float4*>(out + (size_t)token * EMBED + e) = r;
}

extern "C" void kernel_launch(void* const* d_in, const int* in_sizes, int n_in,
                              void* d_out, int out_size, void* d_ws, size_t ws_size,
                              hipStream_t stream)
{
    const int*   x = (const int*)d_in[0];
    const float* W = (const float*)d_in[1];
    const float* b = (const float*)d_in[2];
    float*     out = (float*)d_out;

    if (ws_size >= (size_t)WS_INTS * sizeof(int)) {
        int* ws    = (int*)d_ws;
        int* cnt   = ws + WS_CNT_OFF;
        int* list  = ws + WS_LIST_OFF;
        int* flags = ws + WS_FLAG_OFF;

        k0_zero   <<<(NTILE + 255) / 256, 256, 0, stream>>>(cnt);
        k1_bucket <<<NTOK / 256,          256, 0, stream>>>(x, cnt, list, flags);
        k2_scatter<<<NTILE,               256, 0, stream>>>(W, b, cnt, list, out);
        k3_cleanup<<<NTOK / 256,          256, 0, stream>>>(x, W, b, flags, out);
    } else {
        embed_gather_direct<<<NTOK * 64 / 256, 256, 0, stream>>>(x, W, b, out);
    }
}